// Round 1
// baseline (375.209 us; speedup 1.0000x reference)
//
#include <hip/hip_runtime.h>

// Causal MHA forward, B=4 H=16 S=2048 D=64, fp32 I/O, bf16 MFMA compute.
// One workgroup = 128 q rows of one (b,h); 4 waves x 32 q rows; KV tile = 64.
// S^T = K*Q^T trick keeps softmax row on lane&15 and makes P LDS write b64 /
// read b128 natural.  K LDS stride 72 (balanced b128 banks), V^T stride 68
// (balanced b64 banks), P stride 72.

typedef float  f32x4  __attribute__((ext_vector_type(4)));
typedef short  bf16x8 __attribute__((ext_vector_type(8)));
typedef short  bf16x4 __attribute__((ext_vector_type(4)));

#define NH      16
#define DH      64
#define SEQ     2048
#define NSTATE  1024
#define ROW3    3072
#define BQ      128
#define BK      64
#define KST     72
#define VST     68
#define PST     72
#define NEG_BIG (-1e9f)

static __device__ __forceinline__ short f2bf(float f) {
    unsigned u = __builtin_bit_cast(unsigned, f);
    u += 0x7FFFu + ((u >> 16) & 1u);      // round-to-nearest-even
    return (short)(u >> 16);
}

__global__ __launch_bounds__(256)
void mha_fwd(const float* __restrict__ x, float* __restrict__ out) {
    const int tid  = threadIdx.x;
    const int wave = tid >> 6;
    const int lane = tid & 63;
    const int l16  = lane & 15;
    const int quad = lane >> 4;

    const int q0 = blockIdx.x * BQ;
    const int bh = blockIdx.y;
    const int b  = bh >> 4;
    const int h  = bh & 15;

    const float* xb    = x + (size_t)b * SEQ * ROW3;
    const float* kbase = xb + NSTATE + h * DH;
    const float* vbase = xb + 2 * NSTATE + h * DH;

    __shared__ short Klds[BK * KST];          // K[kv][d], bf16
    __shared__ short Vlds[DH * VST];          // V^T[d][kv], bf16
    __shared__ short Plds[4][2][16 * PST];    // per-wave, per-strip P[q][kv]

    // ---- Q fragments (B-operand of S^T = K*Q^T), pre-scaled by 1/8 ----
    bf16x8 qf[2][2];
#pragma unroll
    for (int s = 0; s < 2; ++s) {
        const int qrow = q0 + wave * 32 + s * 16 + l16;
        const float* qp = xb + (size_t)qrow * ROW3 + h * DH + quad * 8;
#pragma unroll
        for (int f = 0; f < 2; ++f) {
            float4 a = *(const float4*)(qp + 32 * f);
            float4 c = *(const float4*)(qp + 32 * f + 4);
            bf16x8 v;
            v[0] = f2bf(a.x * 0.125f); v[1] = f2bf(a.y * 0.125f);
            v[2] = f2bf(a.z * 0.125f); v[3] = f2bf(a.w * 0.125f);
            v[4] = f2bf(c.x * 0.125f); v[5] = f2bf(c.y * 0.125f);
            v[6] = f2bf(c.z * 0.125f); v[7] = f2bf(c.w * 0.125f);
            qf[s][f] = v;
        }
    }

    f32x4 o[2][4];
#pragma unroll
    for (int s = 0; s < 2; ++s)
#pragma unroll
        for (int t = 0; t < 4; ++t)
            o[s][t] = (f32x4){0.f, 0.f, 0.f, 0.f};
    float m_run[2] = {-3e38f, -3e38f};
    float l_run[2] = {0.f, 0.f};

    const int ntiles = q0 / BK + 2;   // causal: last kv tile index = (q0+127)/64
    for (int it = 0; it < ntiles; ++it) {
        const int kv0 = it * BK;
        __syncthreads();   // protect K/V LDS reuse from previous iteration

        // ---- stage K tile: fp32 global -> bf16 LDS, row-major ----
#pragma unroll
        for (int i = 0; i < 8; ++i) {
            int p  = tid + 256 * i;
            int kv = p >> 5;
            int d  = (p & 31) * 2;
            const float* gp = kbase + (size_t)(kv0 + kv) * ROW3 + d;
            float2 v = *(const float2*)gp;
            unsigned pk = (unsigned)(unsigned short)f2bf(v.x) |
                          ((unsigned)(unsigned short)f2bf(v.y) << 16);
            *(unsigned*)&Klds[kv * KST + d] = pk;
        }
        // ---- stage V tile transposed: Vlds[d][kv] ----
#pragma unroll
        for (int i = 0; i < 8; ++i) {
            int idx = tid + 256 * i;
            int d   = idx & 63;
            int kv  = (idx >> 6) * 2;
            const float* gp = vbase + (size_t)(kv0 + kv) * ROW3 + d;
            float v0 = gp[0];
            float v1 = gp[ROW3];
            unsigned pk = (unsigned)(unsigned short)f2bf(v0) |
                          ((unsigned)(unsigned short)f2bf(v1) << 16);
            *(unsigned*)&Vlds[d * VST + kv] = pk;
        }
        __syncthreads();

        // ---- K fragments (A-operand): K[16t+l16][8*quad + 32f + j] ----
        bf16x8 kf[4][2];
#pragma unroll
        for (int t = 0; t < 4; ++t)
#pragma unroll
            for (int f = 0; f < 2; ++f)
                kf[t][f] = *(const bf16x8*)&Klds[(16 * t + l16) * KST + quad * 8 + 32 * f];
        // ---- V fragments (B-operand): V[8q+32f+j][16t+l16] from V^T ----
        bf16x8 vf[4][2];
#pragma unroll
        for (int t = 0; t < 4; ++t)
#pragma unroll
            for (int f = 0; f < 2; ++f) {
                bf16x4 lo = *(const bf16x4*)&Vlds[(16 * t + l16) * VST + quad * 8 + 32 * f];
                bf16x4 hi = *(const bf16x4*)&Vlds[(16 * t + l16) * VST + quad * 8 + 32 * f + 4];
                vf[t][f] = __builtin_shufflevector(lo, hi, 0, 1, 2, 3, 4, 5, 6, 7);
            }

#pragma unroll
        for (int s = 0; s < 2; ++s) {
            const int qmin = q0 + wave * 32 + s * 16;
            if (kv0 > qmin + 15) continue;          // strip fully masked (wave-uniform)
            const int qrow = qmin + l16;            // this lane's softmax row

            // S^T tiles: St[kv = 16t+4*quad+r][q = l16]
            f32x4 sc[4];
#pragma unroll
            for (int t = 0; t < 4; ++t) {
                f32x4 c = (f32x4){0.f, 0.f, 0.f, 0.f};
                c = __builtin_amdgcn_mfma_f32_16x16x32_bf16(kf[t][0], qf[s][0], c, 0, 0, 0);
                c = __builtin_amdgcn_mfma_f32_16x16x32_bf16(kf[t][1], qf[s][1], c, 0, 0, 0);
                sc[t] = c;
            }
            if (kv0 + BK - 1 > qmin) {              // tile may cross the diagonal
#pragma unroll
                for (int t = 0; t < 4; ++t)
#pragma unroll
                    for (int r = 0; r < 4; ++r) {
                        int kvg = kv0 + 16 * t + 4 * quad + r;
                        if (kvg > qrow) sc[t][r] = NEG_BIG;
                    }
            }

            // online softmax over this tile's 64 kv (reduce across quads)
            float vmax = sc[0][0];
#pragma unroll
            for (int t = 0; t < 4; ++t)
#pragma unroll
                for (int r = 0; r < 4; ++r) vmax = fmaxf(vmax, sc[t][r]);
            vmax = fmaxf(vmax, __shfl_xor(vmax, 16));
            vmax = fmaxf(vmax, __shfl_xor(vmax, 32));
            const float mnew  = fmaxf(m_run[s], vmax);
            const float alpha = __expf(m_run[s] - mnew);
            m_run[s] = mnew;
            float lsum = 0.f;
#pragma unroll
            for (int t = 0; t < 4; ++t)
#pragma unroll
                for (int r = 0; r < 4; ++r) {
                    float pv = __expf(sc[t][r] - mnew);
                    sc[t][r] = pv;
                    lsum += pv;
                }
            lsum += __shfl_xor(lsum, 16);
            lsum += __shfl_xor(lsum, 32);
            l_run[s] = l_run[s] * alpha + lsum;

            // P[q=l16][kv=16t+4*quad+r] -> LDS (b64 writes)
            short* pb = &Plds[wave][s][0];
#pragma unroll
            for (int t = 0; t < 4; ++t) {
                bf16x4 pk;
                pk[0] = f2bf(sc[t][0]); pk[1] = f2bf(sc[t][1]);
                pk[2] = f2bf(sc[t][2]); pk[3] = f2bf(sc[t][3]);
                *(bf16x4*)&pb[l16 * PST + 16 * t + 4 * quad] = pk;
            }
            __asm__ volatile("s_waitcnt lgkmcnt(0)" ::: "memory");
            bf16x8 pf0 = *(const bf16x8*)&pb[l16 * PST + quad * 8];
            bf16x8 pf1 = *(const bf16x8*)&pb[l16 * PST + quad * 8 + 32];

            // alpha for O rows (row = 4*quad + r lives at lane 4*quad+r)
            float ar[4];
#pragma unroll
            for (int r = 0; r < 4; ++r) ar[r] = __shfl(alpha, 4 * quad + r);
#pragma unroll
            for (int t = 0; t < 4; ++t) {
                f32x4 c = o[s][t];
#pragma unroll
                for (int r = 0; r < 4; ++r) c[r] *= ar[r];
                c = __builtin_amdgcn_mfma_f32_16x16x32_bf16(pf0, vf[t][0], c, 0, 0, 0);
                c = __builtin_amdgcn_mfma_f32_16x16x32_bf16(pf1, vf[t][1], c, 0, 0, 0);
                o[s][t] = c;
            }
        }
    }

    // ---- epilogue: O /= l, store fp32 ----
    float* ob = out + ((size_t)b * SEQ) * NSTATE + h * DH;
#pragma unroll
    for (int s = 0; s < 2; ++s) {
        float linv = 1.0f / l_run[s];
        float lr[4];
#pragma unroll
        for (int r = 0; r < 4; ++r) lr[r] = __shfl(linv, 4 * quad + r);
        const int qrow = q0 + wave * 32 + s * 16 + 4 * quad;
#pragma unroll
        for (int t = 0; t < 4; ++t)
#pragma unroll
            for (int r = 0; r < 4; ++r)
                ob[(size_t)(qrow + r) * NSTATE + 16 * t + l16] = o[s][t][r] * lr[r];
    }
}

extern "C" void kernel_launch(void* const* d_in, const int* in_sizes, int n_in,
                              void* d_out, int out_size, void* d_ws, size_t ws_size,
                              hipStream_t stream) {
    const float* x = (const float*)d_in[0];   // [B,S,3*NSTATE] fp32
    // d_in[1] (attn_mask) is not read: the mask is causal and computed inline.
    float* out = (float*)d_out;               // [B,S,NSTATE] fp32
    dim3 grid(SEQ / BQ, 4 * NH);
    dim3 block(256);
    hipLaunchKernelGGL(mha_fwd, grid, block, 0, stream, x, out);
}

// Round 2
// 269.580 us; speedup vs baseline: 1.3918x; 1.3918x over previous
//
#include <hip/hip_runtime.h>

// Causal MHA forward, B=4 H=16 S=2048 D=64, fp32 I/O, bf16 MFMA compute.
// R2: anti-diagonal q-block pairing for uniform work (34 kv-tiles per WG),
// 512-thread WGs (8 waves, one 16-row q strip per wave), 2 WG/CU steady.
// S^T = K*Q^T keeps the softmax row on lane&15; P does an LDS bounce from
// C-layout to A-operand layout.  K stride 72, V^T stride 68, P stride 72.

typedef float  f32x4  __attribute__((ext_vector_type(4)));
typedef short  bf16x8 __attribute__((ext_vector_type(8)));
typedef short  bf16x4 __attribute__((ext_vector_type(4)));

#define NH      16
#define DH      64
#define SEQ     2048
#define NSTATE  1024
#define ROW3    3072
#define BQ      128
#define BK      64
#define NQB     (SEQ / BQ)      // 16 q-blocks
#define KST     72
#define VST     68
#define PST     72
#define NEG_BIG (-1e9f)

static __device__ __forceinline__ short f2bf(float f) {
    unsigned u = __builtin_bit_cast(unsigned, f);
    u += 0x7FFFu + ((u >> 16) & 1u);      // round-to-nearest-even
    return (short)(u >> 16);
}

__global__ __launch_bounds__(512, 4)
void mha_fwd(const float* __restrict__ x, float* __restrict__ out) {
    const int tid  = threadIdx.x;
    const int wave = tid >> 6;        // 0..7  (one 16-row strip each)
    const int lane = tid & 63;
    const int l16  = lane & 15;
    const int quad = lane >> 4;

    const int pr = blockIdx.x;        // pair index 0..7
    const int bh = blockIdx.y;
    const int b  = bh >> 4;
    const int h  = bh & 15;

    const float* xb    = x + (size_t)b * SEQ * ROW3;
    const float* kbase = xb + NSTATE + h * DH;
    const float* vbase = xb + 2 * NSTATE + h * DH;
    float*       ob    = out + (size_t)b * SEQ * NSTATE + h * DH;

    __shared__ short Klds[BK * KST];       // K[kv][d], bf16
    __shared__ short Vlds[DH * VST];       // V^T[d][kv], bf16
    __shared__ short Plds[8][16 * PST];    // per-wave P[q][kv]

#pragma unroll 1
    for (int ph = 0; ph < 2; ++ph) {
        const int qblk = ph ? (NQB - 1 - pr) : pr;   // pair (i, 15-i): 2i+2 + 32-2i = 34 tiles
        const int q0   = qblk * BQ;
        const int qmin = q0 + wave * 16;             // this wave's strip
        const int qrow = qmin + l16;                 // this lane's softmax row

        // ---- Q fragment (B-operand of S^T = K*Q^T), pre-scaled by 1/8 ----
        bf16x8 qf[2];
        {
            const float* qp = xb + (size_t)qrow * ROW3 + h * DH + quad * 8;
#pragma unroll
            for (int f = 0; f < 2; ++f) {
                float4 a = *(const float4*)(qp + 32 * f);
                float4 c = *(const float4*)(qp + 32 * f + 4);
                bf16x8 v;
                v[0] = f2bf(a.x * 0.125f); v[1] = f2bf(a.y * 0.125f);
                v[2] = f2bf(a.z * 0.125f); v[3] = f2bf(a.w * 0.125f);
                v[4] = f2bf(c.x * 0.125f); v[5] = f2bf(c.y * 0.125f);
                v[6] = f2bf(c.z * 0.125f); v[7] = f2bf(c.w * 0.125f);
                qf[f] = v;
            }
        }

        f32x4 o[4];
#pragma unroll
        for (int t = 0; t < 4; ++t) o[t] = (f32x4){0.f, 0.f, 0.f, 0.f};
        float m_run = -3e38f;
        float l_run = 0.f;

        const int ntiles = q0 / BK + BQ / BK;
        for (int it = 0; it < ntiles; ++it) {
            const int kv0 = it * BK;
            __syncthreads();   // protect K/V/P LDS reuse from previous iteration

            // ---- stage K tile: fp32 global -> bf16 LDS, row-major ----
#pragma unroll
            for (int i = 0; i < 4; ++i) {
                int p  = tid + 512 * i;
                int kv = p >> 5;
                int d  = (p & 31) * 2;
                const float* gp = kbase + (size_t)(kv0 + kv) * ROW3 + d;
                float2 v = *(const float2*)gp;
                unsigned pk = (unsigned)(unsigned short)f2bf(v.x) |
                              ((unsigned)(unsigned short)f2bf(v.y) << 16);
                *(unsigned*)&Klds[kv * KST + d] = pk;
            }
            // ---- stage V tile transposed: Vlds[d][kv] ----
#pragma unroll
            for (int i = 0; i < 4; ++i) {
                int idx = tid + 512 * i;
                int d   = idx & 63;
                int kv  = (idx >> 6) * 2;
                const float* gp = vbase + (size_t)(kv0 + kv) * ROW3 + d;
                float v0 = gp[0];
                float v1 = gp[ROW3];
                unsigned pk = (unsigned)(unsigned short)f2bf(v0) |
                              ((unsigned)(unsigned short)f2bf(v1) << 16);
                *(unsigned*)&Vlds[d * VST + kv] = pk;
            }
            __syncthreads();

            if (kv0 > qmin + 15) continue;   // strip fully masked (wave-uniform)

            // ---- K fragments (A-operand): K[16t+l16][8*quad + 32f + j] ----
            bf16x8 kf[4][2];
#pragma unroll
            for (int t = 0; t < 4; ++t)
#pragma unroll
                for (int f = 0; f < 2; ++f)
                    kf[t][f] = *(const bf16x8*)&Klds[(16 * t + l16) * KST + quad * 8 + 32 * f];
            // ---- V fragments (B-operand): V[8q+32f+j][16t+l16] from V^T ----
            bf16x8 vf[4][2];
#pragma unroll
            for (int t = 0; t < 4; ++t)
#pragma unroll
                for (int f = 0; f < 2; ++f) {
                    bf16x4 lo = *(const bf16x4*)&Vlds[(16 * t + l16) * VST + quad * 8 + 32 * f];
                    bf16x4 hi = *(const bf16x4*)&Vlds[(16 * t + l16) * VST + quad * 8 + 32 * f + 4];
                    vf[t][f] = __builtin_shufflevector(lo, hi, 0, 1, 2, 3, 4, 5, 6, 7);
                }

            // S^T tiles: St[kv = 16t+4*quad+r][q = l16]
            f32x4 sc[4];
#pragma unroll
            for (int t = 0; t < 4; ++t) {
                f32x4 c = (f32x4){0.f, 0.f, 0.f, 0.f};
                c = __builtin_amdgcn_mfma_f32_16x16x32_bf16(kf[t][0], qf[0], c, 0, 0, 0);
                c = __builtin_amdgcn_mfma_f32_16x16x32_bf16(kf[t][1], qf[1], c, 0, 0, 0);
                sc[t] = c;
            }
            if (kv0 + BK - 1 > qmin) {        // tile may cross the diagonal
#pragma unroll
                for (int t = 0; t < 4; ++t)
#pragma unroll
                    for (int r = 0; r < 4; ++r) {
                        int kvg = kv0 + 16 * t + 4 * quad + r;
                        if (kvg > qrow) sc[t][r] = NEG_BIG;
                    }
            }

            // online softmax over this tile's 64 kv (reduce across quads)
            float vmax = sc[0][0];
#pragma unroll
            for (int t = 0; t < 4; ++t)
#pragma unroll
                for (int r = 0; r < 4; ++r) vmax = fmaxf(vmax, sc[t][r]);
            vmax = fmaxf(vmax, __shfl_xor(vmax, 16));
            vmax = fmaxf(vmax, __shfl_xor(vmax, 32));
            const float mnew  = fmaxf(m_run, vmax);
            const float alpha = __expf(m_run - mnew);
            m_run = mnew;
            float lsum = 0.f;
#pragma unroll
            for (int t = 0; t < 4; ++t)
#pragma unroll
                for (int r = 0; r < 4; ++r) {
                    float pv = __expf(sc[t][r] - mnew);
                    sc[t][r] = pv;
                    lsum += pv;
                }
            lsum += __shfl_xor(lsum, 16);
            lsum += __shfl_xor(lsum, 32);
            l_run = l_run * alpha + lsum;

            // P[q=l16][kv=16t+4*quad+r] -> LDS (b64 writes)
            short* pb = &Plds[wave][0];
#pragma unroll
            for (int t = 0; t < 4; ++t) {
                bf16x4 pk;
                pk[0] = f2bf(sc[t][0]); pk[1] = f2bf(sc[t][1]);
                pk[2] = f2bf(sc[t][2]); pk[3] = f2bf(sc[t][3]);
                *(bf16x4*)&pb[l16 * PST + 16 * t + 4 * quad] = pk;
            }
            __asm__ volatile("s_waitcnt lgkmcnt(0)" ::: "memory");
            bf16x8 pf0 = *(const bf16x8*)&pb[l16 * PST + quad * 8];
            bf16x8 pf1 = *(const bf16x8*)&pb[l16 * PST + quad * 8 + 32];

            // alpha for O rows (row = 4*quad + r lives at lane 4*quad+r)
            float ar[4];
#pragma unroll
            for (int r = 0; r < 4; ++r) ar[r] = __shfl(alpha, 4 * quad + r);
#pragma unroll
            for (int t = 0; t < 4; ++t) {
                f32x4 c = o[t];
#pragma unroll
                for (int r = 0; r < 4; ++r) c[r] *= ar[r];
                c = __builtin_amdgcn_mfma_f32_16x16x32_bf16(pf0, vf[t][0], c, 0, 0, 0);
                c = __builtin_amdgcn_mfma_f32_16x16x32_bf16(pf1, vf[t][1], c, 0, 0, 0);
                o[t] = c;
            }
        }

        // ---- epilogue: O /= l, store fp32 ----
        {
            float linv = 1.0f / l_run;
            float lr[4];
#pragma unroll
            for (int r = 0; r < 4; ++r) lr[r] = __shfl(linv, 4 * quad + r);
            const int qtop = qmin + 4 * quad;
#pragma unroll
            for (int t = 0; t < 4; ++t)
#pragma unroll
                for (int r = 0; r < 4; ++r)
                    ob[(size_t)(qtop + r) * NSTATE + 16 * t + l16] = o[t][r] * lr[r];
        }
    }
}

extern "C" void kernel_launch(void* const* d_in, const int* in_sizes, int n_in,
                              void* d_out, int out_size, void* d_ws, size_t ws_size,
                              hipStream_t stream) {
    const float* x = (const float*)d_in[0];   // [B,S,3*NSTATE] fp32
    // d_in[1] (attn_mask) is not read: the mask is causal and computed inline.
    float* out = (float*)d_out;               // [B,S,NSTATE] fp32
    dim3 grid(NQB / 2, 4 * NH);               // 8 pairs x 64 (b,h)
    dim3 block(512);
    hipLaunchKernelGGL(mha_fwd, grid, block, 0, stream, x, out);
}